// Round 1
// baseline (3534.164 us; speedup 1.0000x reference)
//
#include <hip/hip_runtime.h>
#include <math.h>

// Problem constants
#define S_  1024
#define B_  8
#define D_  512
#define H_  8
#define HD_ 64
#define FF_ 2048
#define M_  8192   // S*B tokens; token r = s*B_ + b (input [S,B,D] flat order)

// ---------------------------------------------------------------------------
// elementwise add: qk_in = src + pos
// ---------------------------------------------------------------------------
__global__ __launch_bounds__(256) void add_kernel(const float* __restrict__ a,
                                                  const float* __restrict__ b,
                                                  float* __restrict__ o, int n) {
  int i = blockIdx.x * 256 + threadIdx.x;
  if (i < n) o[i] = a[i] + b[i];
}

// ---------------------------------------------------------------------------
// fp32 tiled GEMM: Y = X @ W^T + bias (+res) (+relu)
// X: [M,K] row-major, W: [N,K] row-major (torch Linear weight), bias: [N]
// res: [M,N] residual or nullptr
// flags: bit0 = relu, bit1 = scatter output to [B,H,S,HD] head layout
// tile 64x64, BK=16, block 256 (16x16 threads, 4x4 micro-tile each)
// ---------------------------------------------------------------------------
__global__ __launch_bounds__(256) void gemm_kernel(const float* __restrict__ X,
    const float* __restrict__ W, const float* __restrict__ bias,
    const float* __restrict__ res, float* __restrict__ Y,
    int M, int N, int K, int flags)
{
  __shared__ float As[16][68];   // pad 68: conflict-free stores, 16B-aligned rows
  __shared__ float Bs[16][68];
  int tid = threadIdx.x;
  int m0 = blockIdx.y * 64, n0 = blockIdx.x * 64;
  int tx = tid & 15, ty = tid >> 4;
  float acc[4][4] = {{0.f}};
  for (int k0 = 0; k0 < K; k0 += 16) {
    #pragma unroll
    for (int i = 0; i < 4; i++) {
      int idx = i * 256 + tid;       // 0..1023 -> (mm, kk); 16 consec lanes = 64B seg
      int mm = idx >> 4, kk = idx & 15;
      As[kk][mm] = X[(size_t)(m0 + mm) * K + k0 + kk];
      Bs[kk][mm] = W[(size_t)(n0 + mm) * K + k0 + kk];
    }
    __syncthreads();
    #pragma unroll
    for (int kk = 0; kk < 16; kk++) {
      float4 a4 = *(const float4*)(&As[kk][ty * 4]);
      float4 b4 = *(const float4*)(&Bs[kk][tx * 4]);
      float a[4] = {a4.x, a4.y, a4.z, a4.w};
      float b[4] = {b4.x, b4.y, b4.z, b4.w};
      #pragma unroll
      for (int i = 0; i < 4; i++)
        #pragma unroll
        for (int j = 0; j < 4; j++)
          acc[i][j] += a[i] * b[j];
    }
    __syncthreads();
  }
  #pragma unroll
  for (int i = 0; i < 4; i++) {
    int m = m0 + ty * 4 + i;
    #pragma unroll
    for (int j = 0; j < 4; j++) {
      int n = n0 + tx * 4 + j;
      float v = acc[i][j] + bias[n];
      if (res) v += res[(size_t)m * N + n];
      if (flags & 1) v = fmaxf(v, 0.0f);
      if (flags & 2) {
        // token m = s*B+b, col n = h*64+hd  ->  [B,H,S,HD]
        int s = m >> 3, bb = m & 7, h = n >> 6, hd = n & 63;
        Y[(((size_t)(bb * H_ + h)) * S_ + s) * HD_ + hd] = v;
      } else {
        Y[(size_t)m * N + n] = v;
      }
    }
  }
}

// ---------------------------------------------------------------------------
// LayerNorm (biased var, eps=1e-5): one block per token row of 512
// ---------------------------------------------------------------------------
__global__ __launch_bounds__(256) void ln_kernel(const float* __restrict__ X,
    float* __restrict__ Y, const float* __restrict__ g, const float* __restrict__ bta)
{
  int row = blockIdx.x, tid = threadIdx.x;
  const float* x = X + (size_t)row * D_;
  float v0 = x[tid], v1 = x[tid + 256];
  float s = v0 + v1, q = v0 * v0 + v1 * v1;
  #pragma unroll
  for (int msk = 1; msk < 64; msk <<= 1) {
    s += __shfl_xor(s, msk);
    q += __shfl_xor(q, msk);
  }
  __shared__ float ss[4], qs[4];
  int wid = tid >> 6;
  if ((tid & 63) == 0) { ss[wid] = s; qs[wid] = q; }
  __syncthreads();
  s = ss[0] + ss[1] + ss[2] + ss[3];
  q = qs[0] + qs[1] + qs[2] + qs[3];
  float mean = s * (1.0f / D_);
  float var  = q * (1.0f / D_) - mean * mean;   // biased, matches jnp.var / torch LN
  float inv  = rsqrtf(var + 1e-5f);
  float* y = Y + (size_t)row * D_;
  y[tid]       = (v0 - mean) * inv * g[tid]       + bta[tid];
  y[tid + 256] = (v1 - mean) * inv * g[tid + 256] + bta[tid + 256];
}

// ---------------------------------------------------------------------------
// Fused dual-stream cross-blended attention (flash-style online softmax).
// sh_img == sh_dpt == 0.5*(A_img + A_dpt) since ALPHA=BETA=0.5, so:
//   o_img = 0.5*(A_img@V_img + A_dpt@V_img), o_dpt = 0.5*(A_dpt@V_dpt + A_img@V_dpt)
// 4 accumulators sharing 2 softmax stats. Q/K/V layout [B*H, S, 64] fp32.
// Block: 256 threads = 32 q-rows x 8 col-groups (8 cols each). Key tiles of 32.
// Output scattered to token layout [r=s*B+b, h*64+c].
// ---------------------------------------------------------------------------
__global__ __launch_bounds__(256) void attn_kernel(
    const float* __restrict__ qi, const float* __restrict__ ki, const float* __restrict__ vi,
    const float* __restrict__ qd, const float* __restrict__ kd, const float* __restrict__ vd,
    float* __restrict__ oi, float* __restrict__ od)
{
  int bh = blockIdx.y;                  // 0..63
  int b = bh >> 3, h = bh & 7;
  int q0 = blockIdx.x * 32;
  size_t base = (size_t)bh * S_ * HD_;

  __shared__ float Qs[2][32][68];       // pad 68: 16B-aligned rows, conflict-free
  __shared__ float Ks[2][32][68];
  __shared__ float Vs[2][32][68];
  __shared__ float Ps[2][32][33];       // pad 33: kills 32-way column-read conflict

  int tid = threadIdx.x;
  int row = tid >> 3, cg = tid & 7, c0 = cg * 8;

  // load Q tiles (both streams), coalesced
  #pragma unroll
  for (int it = 0; it < 8; it++) {
    int idx = it * 256 + tid;           // 0..2047
    int i = idx >> 6, d = idx & 63;
    size_t gq = base + (size_t)(q0 + i) * HD_ + d;
    Qs[0][i][d] = qi[gq];
    Qs[1][i][d] = qd[gq];
  }

  float O1[8] = {0.f}, O2[8] = {0.f}, O3[8] = {0.f}, O4[8] = {0.f};
  float mi = -INFINITY, md = -INFINITY, li = 0.f, ld = 0.f;
  const float scale = 0.125f;           // 1/sqrt(64)

  for (int kt = 0; kt < S_ / 32; kt++) {
    __syncthreads();                    // prev PV done before overwriting K/V
    int k0 = kt * 32;
    #pragma unroll
    for (int it = 0; it < 8; it++) {
      int idx = it * 256 + tid;
      int i = idx >> 6, d = idx & 63;
      size_t gk = base + (size_t)(k0 + i) * HD_ + d;
      Ks[0][i][d] = ki[gk]; Ks[1][i][d] = kd[gk];
      Vs[0][i][d] = vi[gk]; Vs[1][i][d] = vd[gk];
    }
    __syncthreads();

    // scores: each thread 4 keys x 2 streams, float4 over d
    {
      float sI[4] = {0.f, 0.f, 0.f, 0.f}, sD[4] = {0.f, 0.f, 0.f, 0.f};
      const float4* qI4 = (const float4*)(&Qs[0][row][0]);
      const float4* qD4 = (const float4*)(&Qs[1][row][0]);
      #pragma unroll
      for (int d4 = 0; d4 < 16; d4++) {
        float4 a0 = qI4[d4];
        float4 a1 = qD4[d4];
        #pragma unroll
        for (int jj = 0; jj < 4; jj++) {
          int j = cg + jj * 8;
          float4 k0v = *(const float4*)(&Ks[0][j][d4 * 4]);
          float4 k1v = *(const float4*)(&Ks[1][j][d4 * 4]);
          sI[jj] += a0.x * k0v.x + a0.y * k0v.y + a0.z * k0v.z + a0.w * k0v.w;
          sD[jj] += a1.x * k1v.x + a1.y * k1v.y + a1.z * k1v.z + a1.w * k1v.w;
        }
      }
      #pragma unroll
      for (int jj = 0; jj < 4; jj++) {
        Ps[0][row][cg + jj * 8] = sI[jj] * scale;
        Ps[1][row][cg + jj * 8] = sD[jj] * scale;
      }
    }
    __syncthreads();

    // online-softmax stats (all 8 threads of a row compute identically)
    float tmi = -INFINITY, tmd = -INFINITY;
    #pragma unroll
    for (int j = 0; j < 32; j++) {
      tmi = fmaxf(tmi, Ps[0][row][j]);
      tmd = fmaxf(tmd, Ps[1][row][j]);
    }
    float mni = fmaxf(mi, tmi), mnd = fmaxf(md, tmd);
    float ai = __expf(mi - mni), ad = __expf(md - mnd);
    float pI[4], pD[4];
    #pragma unroll
    for (int jj = 0; jj < 4; jj++) {
      pI[jj] = __expf(Ps[0][row][cg + jj * 8] - mni);
      pD[jj] = __expf(Ps[1][row][cg + jj * 8] - mnd);
    }
    __syncthreads();                    // everyone done scanning raw scores
    #pragma unroll
    for (int jj = 0; jj < 4; jj++) {
      Ps[0][row][cg + jj * 8] = pI[jj];
      Ps[1][row][cg + jj * 8] = pD[jj];
    }
    __syncthreads();                    // p values visible
    float sumI = 0.f, sumD = 0.f;
    #pragma unroll
    for (int j = 0; j < 32; j++) { sumI += Ps[0][row][j]; sumD += Ps[1][row][j]; }
    li = li * ai + sumI;  ld = ld * ad + sumD;
    mi = mni;  md = mnd;

    #pragma unroll
    for (int c = 0; c < 8; c++) { O1[c] *= ai; O2[c] *= ai; O3[c] *= ad; O4[c] *= ad; }

    // PV accumulate: 4 outer products
    for (int j = 0; j < 32; j++) {
      float pimg = Ps[0][row][j], pdep = Ps[1][row][j];
      float vI[8], vD[8];
      *(float4*)&vI[0] = *(const float4*)(&Vs[0][j][c0]);
      *(float4*)&vI[4] = *(const float4*)(&Vs[0][j][c0 + 4]);
      *(float4*)&vD[0] = *(const float4*)(&Vs[1][j][c0]);
      *(float4*)&vD[4] = *(const float4*)(&Vs[1][j][c0 + 4]);
      #pragma unroll
      for (int c = 0; c < 8; c++) {
        O1[c] += pimg * vI[c];  // P_img @ V_img
        O2[c] += pimg * vD[c];  // P_img @ V_dpt
        O4[c] += pdep * vI[c];  // P_dpt @ V_img
        O3[c] += pdep * vD[c];  // P_dpt @ V_dpt
      }
    }
  }

  float inv_i = 1.0f / li, inv_d = 1.0f / ld;
  int s = q0 + row;
  size_t orow = ((size_t)s * B_ + b) * D_ + h * HD_ + c0;   // token layout
  #pragma unroll
  for (int c = 0; c < 8; c++) {
    oi[orow + c] = 0.5f * (O1[c] * inv_i + O4[c] * inv_d);
    od[orow + c] = 0.5f * (O3[c] * inv_d + O2[c] * inv_i);
  }
}

// ---------------------------------------------------------------------------
extern "C" void kernel_launch(void* const* d_in, const int* in_sizes, int n_in,
                              void* d_out, int out_size, void* d_ws, size_t ws_size,
                              hipStream_t stream) {
  const float* src  = (const float*)d_in[0];
  const float* srcd = (const float*)d_in[1];
  const float* pos  = (const float*)d_in[2];
  const float* wA_i = (const float*)d_in[3];
  const float* bA_i = (const float*)d_in[4];
  const float* wA_d = (const float*)d_in[5];
  const float* bA_d = (const float*)d_in[6];
  const float* w1_i = (const float*)d_in[7];
  const float* b1_i = (const float*)d_in[8];
  const float* w2_i = (const float*)d_in[9];
  const float* b2_i = (const float*)d_in[10];
  const float* w1_d = (const float*)d_in[11];
  const float* b1_d = (const float*)d_in[12];
  const float* w2_d = (const float*)d_in[13];
  const float* b2_d = (const float*)d_in[14];
  const float* ln_i = (const float*)d_in[15];  // [4,512]: g1,b1,g2,b2
  const float* ln_d = (const float*)d_in[16];

  float* out = (float*)d_out;
  float* ws  = (float*)d_ws;
  const size_t T4 = (size_t)M_ * D_;           // 4M floats per [8192,512] buffer

  // workspace: 7 * T4 floats = 112 MB
  float* t_buf = ws;            // qk_in (img), later pre-LN temp
  float* q_i   = ws + 1 * T4;
  float* k_i   = ws + 2 * T4;
  float* v_i   = ws + 3 * T4;
  float* q_d   = ws + 4 * T4;
  float* k_d   = ws + 5 * T4;
  float* v_d   = ws + 6 * T4;
  float* h1    = ws + 1 * T4;   // FFN hidden [8192,2048] = 4*T4, reuses q/k/v (free post-attn)
  float* x_i   = ws + 5 * T4;   // post-LN1 img (reuses k_d)
  float* x_d   = ws + 6 * T4;   // post-LN1 dpt (reuses v_d)
  float* o_i   = out;           // attention outputs parked in d_out (free until final LNs)
  float* o_d   = out + T4;

  dim3 blk(256);
  dim3 gD(D_ / 64, M_ / 64);    // (8,128) for N=512
  dim3 gF(FF_ / 64, M_ / 64);   // (32,128) for N=2048

  // qk_in = src + pos (img stream only; depth has no pos)
  add_kernel<<<dim3((int)(T4 / 256)), blk, 0, stream>>>(src, pos, t_buf, (int)T4);

  // QKV projections -> [B,H,S,64] (flags=2 scatter)
  gemm_kernel<<<gD, blk, 0, stream>>>(t_buf, wA_i + 0 * D_ * D_, bA_i + 0 * D_, nullptr, q_i, M_, D_, D_, 2);
  gemm_kernel<<<gD, blk, 0, stream>>>(t_buf, wA_i + 1 * D_ * D_, bA_i + 1 * D_, nullptr, k_i, M_, D_, D_, 2);
  gemm_kernel<<<gD, blk, 0, stream>>>(src,   wA_i + 2 * D_ * D_, bA_i + 2 * D_, nullptr, v_i, M_, D_, D_, 2);
  gemm_kernel<<<gD, blk, 0, stream>>>(srcd,  wA_d + 0 * D_ * D_, bA_d + 0 * D_, nullptr, q_d, M_, D_, D_, 2);
  gemm_kernel<<<gD, blk, 0, stream>>>(srcd,  wA_d + 1 * D_ * D_, bA_d + 1 * D_, nullptr, k_d, M_, D_, D_, 2);
  gemm_kernel<<<gD, blk, 0, stream>>>(srcd,  wA_d + 2 * D_ * D_, bA_d + 2 * D_, nullptr, v_d, M_, D_, D_, 2);

  // fused cross-blended attention -> o_i, o_d (token layout)
  attn_kernel<<<dim3(S_ / 32, B_ * H_), blk, 0, stream>>>(q_i, k_i, v_i, q_d, k_d, v_d, o_i, o_d);

  // ---- img stream: out-proj + residual, LN1, FFN, LN2 -> out[0..T4) ----
  gemm_kernel<<<gD, blk, 0, stream>>>(o_i, wA_i + 3 * D_ * D_, bA_i + 3 * D_, src, t_buf, M_, D_, D_, 0);
  ln_kernel<<<M_, blk, 0, stream>>>(t_buf, x_i, ln_i + 0 * D_, ln_i + 1 * D_);
  gemm_kernel<<<gF, blk, 0, stream>>>(x_i, w1_i, b1_i, nullptr, h1, M_, FF_, D_, 1);
  gemm_kernel<<<gD, blk, 0, stream>>>(h1, w2_i, b2_i, x_i, t_buf, M_, D_, FF_, 0);
  ln_kernel<<<M_, blk, 0, stream>>>(t_buf, out, ln_i + 2 * D_, ln_i + 3 * D_);

  // ---- depth stream -> out[T4..2*T4) ----
  gemm_kernel<<<gD, blk, 0, stream>>>(o_d, wA_d + 3 * D_ * D_, bA_d + 3 * D_, srcd, t_buf, M_, D_, D_, 0);
  ln_kernel<<<M_, blk, 0, stream>>>(t_buf, x_d, ln_d + 0 * D_, ln_d + 1 * D_);
  gemm_kernel<<<gF, blk, 0, stream>>>(x_d, w1_d, b1_d, nullptr, h1, M_, FF_, D_, 1);
  gemm_kernel<<<gD, blk, 0, stream>>>(h1, w2_d, b2_d, x_d, t_buf, M_, D_, FF_, 0);
  ln_kernel<<<M_, blk, 0, stream>>>(t_buf, out + T4, ln_d + 2 * D_, ln_d + 3 * D_);
}

// Round 2
// 1850.048 us; speedup vs baseline: 1.9103x; 1.9103x over previous
//
#include <hip/hip_runtime.h>
#include <math.h>

// Problem constants
#define S_  1024
#define B_  8
#define D_  512
#define H_  8
#define HD_ 64
#define FF_ 2048
#define M_  8192   // S*B tokens; token r = s*B_ + b

typedef __attribute__((ext_vector_type(8))) short short8;   // 8 x bf16
typedef __attribute__((ext_vector_type(4))) float f32x4;

static __device__ __forceinline__ unsigned short f2bf(float x) {
  union { float f; unsigned int u; } v; v.f = x;
  unsigned int r = v.u + 0x7fff + ((v.u >> 16) & 1);        // RNE
  return (unsigned short)(r >> 16);
}

// ---------------------------------------------------------------------------
__global__ __launch_bounds__(256) void add_kernel(const float* __restrict__ a,
                                                  const float* __restrict__ b,
                                                  float* __restrict__ o, int n) {
  int i = blockIdx.x * 256 + threadIdx.x;
  if (i < n) o[i] = a[i] + b[i];
}

// ---------------------------------------------------------------------------
// fp32 tiled GEMM: Y = X @ W^T + bias (+res) (+relu)
// flags: 1=relu, 2=bf16 head scatter [B,H,S,HD], 4=bf16 transposed scatter
//        [B,H,HD,S], else fp32 row-major [M,N]
// ---------------------------------------------------------------------------
__global__ __launch_bounds__(256) void gemm_kernel(const float* __restrict__ X,
    const float* __restrict__ W, const float* __restrict__ bias,
    const float* __restrict__ res, void* __restrict__ Y,
    int M, int N, int K, int flags)
{
  __shared__ float As[16][68];
  __shared__ float Bs[16][68];
  int tid = threadIdx.x;
  int m0 = blockIdx.y * 64, n0 = blockIdx.x * 64;
  int tx = tid & 15, ty = tid >> 4;
  float acc[4][4] = {{0.f}};
  for (int k0 = 0; k0 < K; k0 += 16) {
    #pragma unroll
    for (int i = 0; i < 4; i++) {
      int idx = i * 256 + tid;
      int mm = idx >> 4, kk = idx & 15;
      As[kk][mm] = X[(size_t)(m0 + mm) * K + k0 + kk];
      Bs[kk][mm] = W[(size_t)(n0 + mm) * K + k0 + kk];
    }
    __syncthreads();
    #pragma unroll
    for (int kk = 0; kk < 16; kk++) {
      float4 a4 = *(const float4*)(&As[kk][ty * 4]);
      float4 b4 = *(const float4*)(&Bs[kk][tx * 4]);
      float a[4] = {a4.x, a4.y, a4.z, a4.w};
      float b[4] = {b4.x, b4.y, b4.z, b4.w};
      #pragma unroll
      for (int i = 0; i < 4; i++)
        #pragma unroll
        for (int j = 0; j < 4; j++)
          acc[i][j] += a[i] * b[j];
    }
    __syncthreads();
  }
  #pragma unroll
  for (int i = 0; i < 4; i++) {
    int m = m0 + ty * 4 + i;
    #pragma unroll
    for (int j = 0; j < 4; j++) {
      int n = n0 + tx * 4 + j;
      float v = acc[i][j] + bias[n];
      if (res) v += res[(size_t)m * N + n];
      if (flags & 1) v = fmaxf(v, 0.0f);
      if (flags & 2) {        // token m=(s,b), col n=(h,hd) -> bf16 [B,H,S,HD]
        int s = m >> 3, bb = m & 7, h = n >> 6, hd = n & 63;
        ((unsigned short*)Y)[(((size_t)(bb * H_ + h)) * S_ + s) * HD_ + hd] = f2bf(v);
      } else if (flags & 4) { // bf16 [B,H,HD,S] (V transposed)
        int s = m >> 3, bb = m & 7, h = n >> 6, hd = n & 63;
        ((unsigned short*)Y)[(((size_t)(bb * H_ + h)) * HD_ + hd) * S_ + s] = f2bf(v);
      } else {
        ((float*)Y)[(size_t)m * N + n] = v;
      }
    }
  }
}

// ---------------------------------------------------------------------------
// LayerNorm (biased var, eps=1e-5): one block per token row of 512
// ---------------------------------------------------------------------------
__global__ __launch_bounds__(256) void ln_kernel(const float* __restrict__ X,
    float* __restrict__ Y, const float* __restrict__ g, const float* __restrict__ bta)
{
  int row = blockIdx.x, tid = threadIdx.x;
  const float* x = X + (size_t)row * D_;
  float v0 = x[tid], v1 = x[tid + 256];
  float s = v0 + v1, q = v0 * v0 + v1 * v1;
  #pragma unroll
  for (int msk = 1; msk < 64; msk <<= 1) {
    s += __shfl_xor(s, msk);
    q += __shfl_xor(q, msk);
  }
  __shared__ float ss[4], qs[4];
  int wid = tid >> 6;
  if ((tid & 63) == 0) { ss[wid] = s; qs[wid] = q; }
  __syncthreads();
  s = ss[0] + ss[1] + ss[2] + ss[3];
  q = qs[0] + qs[1] + qs[2] + qs[3];
  float mean = s * (1.0f / D_);
  float var  = q * (1.0f / D_) - mean * mean;
  float inv  = rsqrtf(var + 1e-5f);
  float* y = Y + (size_t)row * D_;
  y[tid]       = (v0 - mean) * inv * g[tid]       + bta[tid];
  y[tid + 256] = (v1 - mean) * inv * g[tid + 256] + bta[tid + 256];
}

// ---------------------------------------------------------------------------
// MFMA dual-stream cross-blended flash attention (bf16, 16x16x32).
// Logits |s| <~ 1.5 by construction -> plain exp (no max subtraction) is exact
// softmax. 4 unnormalized accumulators (P_i V_i, P_d V_i, P_i V_d, P_d V_d),
// normalize + blend 0.5/0.5 at the end.
// Q,K: bf16 [BH, S, 64]; V: bf16 [BH, 64, S] (transposed at projection).
// Block: 256 thr = 4 waves; wave w handles q-rows q0+16w..+15; K-tiles of 64.
// ---------------------------------------------------------------------------
__global__ __launch_bounds__(256) void attn_kernel(
    const unsigned short* __restrict__ Qi, const unsigned short* __restrict__ Ki,
    const unsigned short* __restrict__ Vi, const unsigned short* __restrict__ Qd,
    const unsigned short* __restrict__ Kd, const unsigned short* __restrict__ Vd,
    float* __restrict__ oi, float* __restrict__ od)
{
  __shared__ __align__(16) unsigned short Ks[2][64][72];   // [stream][key][dim] pad 72
  __shared__ __align__(16) unsigned short Vt[2][64][72];   // [stream][dim][key] pad 72
  __shared__ __align__(16) unsigned short Pl[4][2][16][72];// [wave][stream][qrow][key]

  int tid = threadIdx.x;
  int bh = blockIdx.y;                 // b*H + h
  int b = bh >> 3, h = bh & 7;
  int q0 = blockIdx.x * 64;
  int lane = tid & 63, w = tid >> 6;
  int m = lane & 15, g = lane >> 4;    // g = 0..3

  size_t kvbase = (size_t)bh * S_ * HD_;   // [bh][s][64] element base
  size_t vtbase = (size_t)bh * HD_ * S_;   // [bh][64][1024] element base

  // Q fragments (A-operand): lane holds Q[q0+16w+m][g*8 + c*32 .. +7]
  short8 qfI[2], qfD[2];
  {
    size_t qa = kvbase + (size_t)(q0 + w * 16 + m) * HD_ + g * 8;
    qfI[0] = *(const short8*)(Qi + qa);      qfI[1] = *(const short8*)(Qi + qa + 32);
    qfD[0] = *(const short8*)(Qd + qa);      qfD[1] = *(const short8*)(Qd + qa + 32);
  }

  f32x4 Oii[4], Odi[4], Oid[4], Odd[4];
  #pragma unroll
  for (int n = 0; n < 4; n++) {
    Oii[n] = (f32x4){0.f,0.f,0.f,0.f}; Odi[n] = (f32x4){0.f,0.f,0.f,0.f};
    Oid[n] = (f32x4){0.f,0.f,0.f,0.f}; Odd[n] = (f32x4){0.f,0.f,0.f,0.f};
  }
  float lI[4] = {0.f,0.f,0.f,0.f}, lD[4] = {0.f,0.f,0.f,0.f};
  const float scale = 0.125f;

  for (int kt = 0; kt < S_ / 64; kt++) {
    int k0 = kt * 64;
    __syncthreads();                   // prior iteration's K/V reads done
    #pragma unroll
    for (int half = 0; half < 2; half++) {
      int idx = half * 256 + tid;      // 0..511: row=idx>>3, 8-elem chunk idx&7
      int row = idx >> 3, c8 = (idx & 7) * 8;
      *(uint4*)&Ks[0][row][c8] = *(const uint4*)(Ki + kvbase + (size_t)(k0 + row) * HD_ + c8);
      *(uint4*)&Ks[1][row][c8] = *(const uint4*)(Kd + kvbase + (size_t)(k0 + row) * HD_ + c8);
      *(uint4*)&Vt[0][row][c8] = *(const uint4*)(Vi + vtbase + (size_t)row * S_ + k0 + c8);
      *(uint4*)&Vt[1][row][c8] = *(const uint4*)(Vd + vtbase + (size_t)row * S_ + k0 + c8);
    }
    __syncthreads();

    // ---- QK^T (both streams, 4 key-tiles of 16), exp, stash P in LDS ----
    #pragma unroll
    for (int st = 0; st < 2; st++) {
      const short8* qf = st ? qfD : qfI;
      float* ls = st ? lD : lI;
      #pragma unroll
      for (int n = 0; n < 4; n++) {
        short8 k0f = *(const short8*)&Ks[st][n * 16 + m][g * 8];
        short8 k1f = *(const short8*)&Ks[st][n * 16 + m][g * 8 + 32];
        f32x4 acc = (f32x4){0.f,0.f,0.f,0.f};
        acc = __builtin_amdgcn_mfma_f32_16x16x32_bf16(qf[0], k0f, acc, 0, 0, 0);
        acc = __builtin_amdgcn_mfma_f32_16x16x32_bf16(qf[1], k1f, acc, 0, 0, 0);
        // C layout: col(key within tile)=m, row(q)=g*4+r
        #pragma unroll
        for (int r = 0; r < 4; r++) {
          float p = __expf(acc[r] * scale);
          ls[r] += p;
          Pl[w][st][g * 4 + r][n * 16 + m] = f2bf(p);
        }
      }
    }
    // per-wave LDS round-trip: C-layout -> A-layout (no cross-wave sharing)

    // ---- PV: 4 combos, keys K-dim=64 in 2 chunks of 32 ----
    #pragma unroll
    for (int c = 0; c < 2; c++) {
      short8 pI = *(const short8*)&Pl[w][0][m][g * 8 + c * 32];
      short8 pD = *(const short8*)&Pl[w][1][m][g * 8 + c * 32];
      #pragma unroll
      for (int n = 0; n < 4; n++) {
        short8 vI = *(const short8*)&Vt[0][n * 16 + m][g * 8 + c * 32];
        short8 vD = *(const short8*)&Vt[1][n * 16 + m][g * 8 + c * 32];
        Oii[n] = __builtin_amdgcn_mfma_f32_16x16x32_bf16(pI, vI, Oii[n], 0, 0, 0);
        Odi[n] = __builtin_amdgcn_mfma_f32_16x16x32_bf16(pD, vI, Odi[n], 0, 0, 0);
        Oid[n] = __builtin_amdgcn_mfma_f32_16x16x32_bf16(pI, vD, Oid[n], 0, 0, 0);
        Odd[n] = __builtin_amdgcn_mfma_f32_16x16x32_bf16(pD, vD, Odd[n], 0, 0, 0);
      }
    }
  }

  // reduce softmax denominators across the 16 lanes holding each row
  #pragma unroll
  for (int r = 0; r < 4; r++) {
    #pragma unroll
    for (int msk = 1; msk <= 8; msk <<= 1) {
      lI[r] += __shfl_xor(lI[r], msk);
      lD[r] += __shfl_xor(lD[r], msk);
    }
  }
  float invI[4], invD[4];
  #pragma unroll
  for (int r = 0; r < 4; r++) { invI[r] = 1.0f / lI[r]; invD[r] = 1.0f / lD[r]; }

  // store: row=q0+16w+g*4+r, col=h*64+n*16+m, token layout [s*B+b][512]
  #pragma unroll
  for (int n = 0; n < 4; n++) {
    #pragma unroll
    for (int r = 0; r < 4; r++) {
      int srow = q0 + w * 16 + g * 4 + r;
      size_t o = ((size_t)srow * B_ + b) * D_ + h * HD_ + n * 16 + m;
      oi[o] = 0.5f * (Oii[n][r] * invI[r] + Odi[n][r] * invD[r]);
      od[o] = 0.5f * (Odd[n][r] * invD[r] + Oid[n][r] * invI[r]);
    }
  }
}

// ---------------------------------------------------------------------------
extern "C" void kernel_launch(void* const* d_in, const int* in_sizes, int n_in,
                              void* d_out, int out_size, void* d_ws, size_t ws_size,
                              hipStream_t stream) {
  const float* src  = (const float*)d_in[0];
  const float* srcd = (const float*)d_in[1];
  const float* pos  = (const float*)d_in[2];
  const float* wA_i = (const float*)d_in[3];
  const float* bA_i = (const float*)d_in[4];
  const float* wA_d = (const float*)d_in[5];
  const float* bA_d = (const float*)d_in[6];
  const float* w1_i = (const float*)d_in[7];
  const float* b1_i = (const float*)d_in[8];
  const float* w2_i = (const float*)d_in[9];
  const float* b2_i = (const float*)d_in[10];
  const float* w1_d = (const float*)d_in[11];
  const float* b1_d = (const float*)d_in[12];
  const float* w2_d = (const float*)d_in[13];
  const float* b2_d = (const float*)d_in[14];
  const float* ln_i = (const float*)d_in[15];
  const float* ln_d = (const float*)d_in[16];

  float* out = (float*)d_out;
  float* ws  = (float*)d_ws;
  const size_t T4 = (size_t)M_ * D_;      // 4M elements per [8192,512]

  // fp32 slots
  float* t_buf = ws;                      // [M,D] temp
  float* h1    = ws + 1 * T4;             // FFN hidden [M,FF] (post-attention)
  float* x_i   = ws + 5 * T4;
  float* x_d   = ws + 6 * T4;
  // bf16 QKV region: ws[T4 .. 4*T4) as ushort (6 buffers x T4 elems)
  unsigned short* qkv16 = (unsigned short*)(ws + T4);
  unsigned short* q_i = qkv16 + 0 * T4;
  unsigned short* k_i = qkv16 + 1 * T4;
  unsigned short* v_i = qkv16 + 2 * T4;   // transposed [B,H,HD,S]
  unsigned short* q_d = qkv16 + 3 * T4;
  unsigned short* k_d = qkv16 + 4 * T4;
  unsigned short* v_d = qkv16 + 5 * T4;
  float* o_i = out;                        // attention outputs parked in d_out
  float* o_d = out + T4;

  dim3 blk(256);
  dim3 gD(D_ / 64, M_ / 64);
  dim3 gF(FF_ / 64, M_ / 64);

  add_kernel<<<dim3((int)(T4 / 256)), blk, 0, stream>>>(src, pos, t_buf, (int)T4);

  // QKV projections -> bf16 head layouts (V transposed)
  gemm_kernel<<<gD, blk, 0, stream>>>(t_buf, wA_i + 0 * D_ * D_, bA_i + 0 * D_, nullptr, q_i, M_, D_, D_, 2);
  gemm_kernel<<<gD, blk, 0, stream>>>(t_buf, wA_i + 1 * D_ * D_, bA_i + 1 * D_, nullptr, k_i, M_, D_, D_, 2);
  gemm_kernel<<<gD, blk, 0, stream>>>(src,   wA_i + 2 * D_ * D_, bA_i + 2 * D_, nullptr, v_i, M_, D_, D_, 4);
  gemm_kernel<<<gD, blk, 0, stream>>>(srcd,  wA_d + 0 * D_ * D_, bA_d + 0 * D_, nullptr, q_d, M_, D_, D_, 2);
  gemm_kernel<<<gD, blk, 0, stream>>>(srcd,  wA_d + 1 * D_ * D_, bA_d + 1 * D_, nullptr, k_d, M_, D_, D_, 2);
  gemm_kernel<<<gD, blk, 0, stream>>>(srcd,  wA_d + 2 * D_ * D_, bA_d + 2 * D_, nullptr, v_d, M_, D_, D_, 4);

  attn_kernel<<<dim3(S_ / 64, B_ * H_), blk, 0, stream>>>(q_i, k_i, v_i, q_d, k_d, v_d, o_i, o_d);

  // ---- img stream ----
  gemm_kernel<<<gD, blk, 0, stream>>>(o_i, wA_i + 3 * D_ * D_, bA_i + 3 * D_, src, t_buf, M_, D_, D_, 0);
  ln_kernel<<<M_, blk, 0, stream>>>(t_buf, x_i, ln_i + 0 * D_, ln_i + 1 * D_);
  gemm_kernel<<<gF, blk, 0, stream>>>(x_i, w1_i, b1_i, nullptr, h1, M_, FF_, D_, 1);
  gemm_kernel<<<gD, blk, 0, stream>>>(h1, w2_i, b2_i, x_i, t_buf, M_, D_, FF_, 0);
  ln_kernel<<<M_, blk, 0, stream>>>(t_buf, out, ln_i + 2 * D_, ln_i + 3 * D_);

  // ---- depth stream ----
  gemm_kernel<<<gD, blk, 0, stream>>>(o_d, wA_d + 3 * D_ * D_, bA_d + 3 * D_, srcd, t_buf, M_, D_, D_, 0);
  ln_kernel<<<M_, blk, 0, stream>>>(t_buf, x_d, ln_d + 0 * D_, ln_d + 1 * D_);
  gemm_kernel<<<gF, blk, 0, stream>>>(x_d, w1_d, b1_d, nullptr, h1, M_, FF_, D_, 1);
  gemm_kernel<<<gD, blk, 0, stream>>>(h1, w2_d, b2_d, x_d, t_buf, M_, D_, FF_, 0);
  ln_kernel<<<M_, blk, 0, stream>>>(t_buf, out + T4, ln_d + 2 * D_, ln_d + 3 * D_);
}

// Round 3
// 680.945 us; speedup vs baseline: 5.1901x; 2.7169x over previous
//
#include <hip/hip_runtime.h>
#include <math.h>

// Problem constants
#define S_  1024
#define B_  8
#define D_  512
#define H_  8
#define HD_ 64
#define FF_ 2048
#define M_  8192   // S*B tokens; token r = s*B_ + b
#define DD_ (D_ * D_)

typedef __attribute__((ext_vector_type(8))) short short8;   // 8 x bf16
typedef __attribute__((ext_vector_type(4))) float f32x4;

static __device__ __forceinline__ unsigned short f2bf(float x) {
  union { float f; unsigned int u; } v; v.f = x;
  unsigned int r = v.u + 0x7fff + ((v.u >> 16) & 1);        // RNE
  return (unsigned short)(r >> 16);
}

// async global->LDS, 16B per lane; LDS dest = wave-uniform base + lane*16
static __device__ __forceinline__ void gl_lds16(const unsigned short* g, unsigned short* l) {
  __builtin_amdgcn_global_load_lds((__attribute__((address_space(1))) void*)(g),
                                   (__attribute__((address_space(3))) void*)(l), 16, 0, 0);
}

// ---------------------------------------------------------------------------
// fp32 -> bf16 convert (4 elems/thread)
// ---------------------------------------------------------------------------
__global__ __launch_bounds__(256) void cvt_kernel(const float* __restrict__ in,
    unsigned short* __restrict__ out, int n) {
  int i = (blockIdx.x * 256 + threadIdx.x) * 4;
  if (i >= n) return;
  float4 v = *(const float4*)(in + i);
  unsigned short u[4] = {f2bf(v.x), f2bf(v.y), f2bf(v.z), f2bf(v.w)};
  *(uint2*)(out + i) = *(const uint2*)u;
}

// qk_in = bf16(src + pos)
__global__ __launch_bounds__(256) void addcvt_kernel(const float* __restrict__ a,
    const float* __restrict__ b, unsigned short* __restrict__ out, int n) {
  int i = (blockIdx.x * 256 + threadIdx.x) * 4;
  if (i >= n) return;
  float4 va = *(const float4*)(a + i);
  float4 vb = *(const float4*)(b + i);
  unsigned short u[4] = {f2bf(va.x + vb.x), f2bf(va.y + vb.y),
                         f2bf(va.z + vb.z), f2bf(va.w + vb.w)};
  *(uint2*)(out + i) = *(const uint2*)u;
}

// ---------------------------------------------------------------------------
// bf16 MFMA GEMM (m97 structure): Y = X @ W^T + bias (+res) (+relu)
// X: [M,K] bf16 row-major, W: [N,K] bf16 row-major, bias fp32 [N],
// res fp32 [M,N] or null. Yf fp32 out (nullable), Yb bf16 out (nullable).
// 128x128 tile, BK=32, 256 thr = 4 waves (2x2 of 64x64), 16x16x32 MFMA.
// Staging via global_load_lds width=16 (As/Bs unpadded, lane-order layout).
// ---------------------------------------------------------------------------
__global__ __launch_bounds__(256) void mgemm_kernel(
    const unsigned short* __restrict__ X, const unsigned short* __restrict__ W,
    const float* __restrict__ bias, const float* __restrict__ res,
    float* __restrict__ Yf, unsigned short* __restrict__ Yb,
    int M, int N, int K, int relu)
{
  __shared__ unsigned short As[128 * 32];
  __shared__ unsigned short Bs[128 * 32];
  int tid = threadIdx.x;
  int lane = tid & 63, w = tid >> 6;
  int ml = lane & 15, g = lane >> 4;
  int wm = w >> 1, wn = w & 1;
  int m0 = blockIdx.y * 128, n0 = blockIdx.x * 128;

  // staging: wave w covers rows w*32..w*32+31 (2 chunks of 16 rows);
  // lane l -> row base + l/4, 16B chunk (l&3) within the 64B row
  int lrow = w * 32 + (lane >> 2);
  int lcol = (lane & 3) * 8;
  const unsigned short* gA = X + (size_t)(m0 + lrow) * K + lcol;
  const unsigned short* gB = W + (size_t)(n0 + lrow) * K + lcol;
  unsigned short* lA = &As[w * 1024];
  unsigned short* lB = &Bs[w * 1024];

  f32x4 acc[4][4];
  #pragma unroll
  for (int i = 0; i < 4; i++)
    #pragma unroll
    for (int j = 0; j < 4; j++) acc[i][j] = (f32x4){0.f, 0.f, 0.f, 0.f};

  for (int k0 = 0; k0 < K; k0 += 32) {
    __syncthreads();                 // LDS readers from prev iter done
    gl_lds16(gA + k0, lA);
    gl_lds16(gA + k0 + (size_t)16 * K, lA + 512);
    gl_lds16(gB + k0, lB);
    gl_lds16(gB + k0 + (size_t)16 * K, lB + 512);
    __syncthreads();                 // drains vmcnt(0): staged data visible

    short8 af[4], bfr[4];
    #pragma unroll
    for (int i = 0; i < 4; i++)
      af[i] = *(const short8*)&As[(wm * 64 + i * 16 + ml) * 32 + g * 8];
    #pragma unroll
    for (int j = 0; j < 4; j++)
      bfr[j] = *(const short8*)&Bs[(wn * 64 + j * 16 + ml) * 32 + g * 8];
    #pragma unroll
    for (int i = 0; i < 4; i++)
      #pragma unroll
      for (int j = 0; j < 4; j++)
        acc[i][j] = __builtin_amdgcn_mfma_f32_16x16x32_bf16(af[i], bfr[j], acc[i][j], 0, 0, 0);
  }

  // epilogue: C/D layout col=lane&15 (N dim), row=g*4+r (M dim)
  #pragma unroll
  for (int i = 0; i < 4; i++) {
    int grow = m0 + wm * 64 + i * 16 + g * 4;
    #pragma unroll
    for (int j = 0; j < 4; j++) {
      int gcol = n0 + wn * 64 + j * 16 + ml;
      float bv = bias[gcol];
      #pragma unroll
      for (int r = 0; r < 4; r++) {
        float v = acc[i][j][r] + bv;
        if (res) v += res[(size_t)(grow + r) * N + gcol];
        if (relu) v = fmaxf(v, 0.0f);
        if (Yf) Yf[(size_t)(grow + r) * N + gcol] = v;
        if (Yb) Yb[(size_t)(grow + r) * N + gcol] = f2bf(v);
      }
    }
  }
}

// ---------------------------------------------------------------------------
// V transpose: v [M=8192, ld] token-major head slice -> vt [B*H][64][1024]
// ---------------------------------------------------------------------------
__global__ __launch_bounds__(256) void vtrans_kernel(const unsigned short* __restrict__ v,
    int ld, unsigned short* __restrict__ vt) {
  __shared__ unsigned short tile[64][72];
  int bh = blockIdx.y, b = bh >> 3, h = bh & 7;
  int s0 = blockIdx.x * 64;
  int tid = threadIdx.x;
  #pragma unroll
  for (int t = 0; t < 2; t++) {
    int idx = t * 256 + tid;
    int i = idx >> 3, c8 = (idx & 7) * 8;
    *(uint4*)&tile[i][c8] =
        *(const uint4*)(v + ((size_t)(s0 + i) * B_ + b) * ld + h * HD_ + c8);
  }
  __syncthreads();
  int hd = tid >> 2, j0 = (tid & 3) * 16;
  unsigned short tmp[16];
  #pragma unroll
  for (int j = 0; j < 16; j++) tmp[j] = tile[j0 + j][hd];
  unsigned short* dst = vt + ((size_t)bh * HD_ + hd) * S_ + s0 + j0;
  *(uint4*)(dst) = *(const uint4*)&tmp[0];
  *(uint4*)(dst + 8) = *(const uint4*)&tmp[8];
}

// ---------------------------------------------------------------------------
// LayerNorm (biased var, eps=1e-5): one block per token row of 512
// Yf fp32 (always), Yb bf16 (nullable)
// ---------------------------------------------------------------------------
__global__ __launch_bounds__(256) void ln_kernel(const float* __restrict__ X,
    float* __restrict__ Yf, unsigned short* __restrict__ Yb,
    const float* __restrict__ g, const float* __restrict__ bta)
{
  int row = blockIdx.x, tid = threadIdx.x;
  const float* x = X + (size_t)row * D_;
  float v0 = x[tid], v1 = x[tid + 256];
  float s = v0 + v1, q = v0 * v0 + v1 * v1;
  #pragma unroll
  for (int msk = 1; msk < 64; msk <<= 1) {
    s += __shfl_xor(s, msk);
    q += __shfl_xor(q, msk);
  }
  __shared__ float ss[4], qs[4];
  int wid = tid >> 6;
  if ((tid & 63) == 0) { ss[wid] = s; qs[wid] = q; }
  __syncthreads();
  s = ss[0] + ss[1] + ss[2] + ss[3];
  q = qs[0] + qs[1] + qs[2] + qs[3];
  float mean = s * (1.0f / D_);
  float var  = q * (1.0f / D_) - mean * mean;
  float inv  = rsqrtf(var + 1e-5f);
  float o0 = (v0 - mean) * inv * g[tid]       + bta[tid];
  float o1 = (v1 - mean) * inv * g[tid + 256] + bta[tid + 256];
  float* y = Yf + (size_t)row * D_;
  y[tid] = o0;  y[tid + 256] = o1;
  if (Yb) {
    unsigned short* yb = Yb + (size_t)row * D_;
    yb[tid] = f2bf(o0);  yb[tid + 256] = f2bf(o1);
  }
}

// ---------------------------------------------------------------------------
// MFMA dual-stream cross-blended flash attention (bf16, 16x16x32).
// Logits small (|s|<~1.5) -> plain exp == exact softmax (no max subtraction).
// Q,K token-major bf16 with leading dims ldi/ldd; V pre-transposed [BH][64][S].
// Outputs bf16 token-major [M][512].
// ---------------------------------------------------------------------------
__global__ __launch_bounds__(256) void attn_kernel(
    const unsigned short* __restrict__ Qi, const unsigned short* __restrict__ Ki, int ldi,
    const unsigned short* __restrict__ Vti,
    const unsigned short* __restrict__ Qd, const unsigned short* __restrict__ Kd, int ldd,
    const unsigned short* __restrict__ Vtd,
    unsigned short* __restrict__ oi, unsigned short* __restrict__ od)
{
  __shared__ __align__(16) unsigned short Ks[2][64][72];
  __shared__ __align__(16) unsigned short Vt[2][64][72];
  __shared__ __align__(16) unsigned short Pl[4][2][16][72];

  int tid = threadIdx.x;
  int bh = blockIdx.y, b = bh >> 3, h = bh & 7;
  int q0 = blockIdx.x * 64;
  int lane = tid & 63, w = tid >> 6;
  int m = lane & 15, g = lane >> 4;

  size_t vtbase = (size_t)bh * HD_ * S_;

  short8 qfI[2], qfD[2];
  {
    size_t tok = (size_t)(q0 + w * 16 + m) * B_ + b;
    const unsigned short* qa_i = Qi + tok * ldi + h * HD_ + g * 8;
    const unsigned short* qa_d = Qd + tok * ldd + h * HD_ + g * 8;
    qfI[0] = *(const short8*)(qa_i);  qfI[1] = *(const short8*)(qa_i + 32);
    qfD[0] = *(const short8*)(qa_d);  qfD[1] = *(const short8*)(qa_d + 32);
  }

  f32x4 Oii[4], Odi[4], Oid[4], Odd[4];
  #pragma unroll
  for (int n = 0; n < 4; n++) {
    Oii[n] = (f32x4){0.f,0.f,0.f,0.f}; Odi[n] = (f32x4){0.f,0.f,0.f,0.f};
    Oid[n] = (f32x4){0.f,0.f,0.f,0.f}; Odd[n] = (f32x4){0.f,0.f,0.f,0.f};
  }
  float lI[4] = {0.f,0.f,0.f,0.f}, lD[4] = {0.f,0.f,0.f,0.f};
  const float scale = 0.125f;

  for (int kt = 0; kt < S_ / 64; kt++) {
    int k0 = kt * 64;
    __syncthreads();
    #pragma unroll
    for (int half = 0; half < 2; half++) {
      int idx = half * 256 + tid;
      int row = idx >> 3, c8 = (idx & 7) * 8;
      size_t ktok = (size_t)(k0 + row) * B_ + b;
      *(uint4*)&Ks[0][row][c8] = *(const uint4*)(Ki + ktok * ldi + h * HD_ + c8);
      *(uint4*)&Ks[1][row][c8] = *(const uint4*)(Kd + ktok * ldd + h * HD_ + c8);
      *(uint4*)&Vt[0][row][c8] = *(const uint4*)(Vti + vtbase + (size_t)row * S_ + k0 + c8);
      *(uint4*)&Vt[1][row][c8] = *(const uint4*)(Vtd + vtbase + (size_t)row * S_ + k0 + c8);
    }
    __syncthreads();

    // QK^T (4 key-tiles of 16 per stream), exp, stash P in per-wave LDS
    #pragma unroll
    for (int st = 0; st < 2; st++) {
      const short8* qf = st ? qfD : qfI;
      float* ls = st ? lD : lI;
      #pragma unroll
      for (int n = 0; n < 4; n++) {
        short8 k0f = *(const short8*)&Ks[st][n * 16 + m][g * 8];
        short8 k1f = *(const short8*)&Ks[st][n * 16 + m][g * 8 + 32];
        f32x4 accs = (f32x4){0.f,0.f,0.f,0.f};
        accs = __builtin_amdgcn_mfma_f32_16x16x32_bf16(qf[0], k0f, accs, 0, 0, 0);
        accs = __builtin_amdgcn_mfma_f32_16x16x32_bf16(qf[1], k1f, accs, 0, 0, 0);
        #pragma unroll
        for (int r = 0; r < 4; r++) {
          float p = __expf(accs[r] * scale);
          ls[r] += p;
          Pl[w][st][g * 4 + r][n * 16 + m] = f2bf(p);
        }
      }
    }

    // PV: 4 combos, K-dim 64 keys in 2 chunks of 32
    #pragma unroll
    for (int c = 0; c < 2; c++) {
      short8 pI = *(const short8*)&Pl[w][0][m][g * 8 + c * 32];
      short8 pD = *(const short8*)&Pl[w][1][m][g * 8 + c * 32];
      #pragma unroll
      for (int n = 0; n < 4; n++) {
        short8 vI = *(const short8*)&Vt[0][n * 16 + m][g * 8 + c * 32];
        short8 vD = *(const short8*)&Vt[1][n * 16 + m][g * 8 + c * 32];
        Oii[n] = __builtin_amdgcn_mfma_f32_16x16x32_bf16(pI, vI, Oii[n], 0, 0, 0);
        Odi[n] = __builtin_amdgcn_mfma_f32_16x16x32_bf16(pD, vI, Odi[n], 0, 0, 0);
        Oid[n] = __builtin_amdgcn_mfma_f32_16x16x32_bf16(pI, vD, Oid[n], 0, 0, 0);
        Odd[n] = __builtin_amdgcn_mfma_f32_16x16x32_bf16(pD, vD, Odd[n], 0, 0, 0);
      }
    }
  }

  #pragma unroll
  for (int r = 0; r < 4; r++) {
    #pragma unroll
    for (int msk = 1; msk <= 8; msk <<= 1) {
      lI[r] += __shfl_xor(lI[r], msk);
      lD[r] += __shfl_xor(lD[r], msk);
    }
  }
  float invI[4], invD[4];
  #pragma unroll
  for (int r = 0; r < 4; r++) { invI[r] = 1.0f / lI[r]; invD[r] = 1.0f / lD[r]; }

  #pragma unroll
  for (int n = 0; n < 4; n++) {
    #pragma unroll
    for (int r = 0; r < 4; r++) {
      int srow = q0 + w * 16 + g * 4 + r;
      size_t o = ((size_t)srow * B_ + b) * D_ + h * HD_ + n * 16 + m;
      oi[o] = f2bf(0.5f * (Oii[n][r] * invI[r] + Odi[n][r] * invD[r]));
      od[o] = f2bf(0.5f * (Odd[n][r] * invD[r] + Oid[n][r] * invI[r]));
    }
  }
}

// ---------------------------------------------------------------------------
extern "C" void kernel_launch(void* const* d_in, const int* in_sizes, int n_in,
                              void* d_out, int out_size, void* d_ws, size_t ws_size,
                              hipStream_t stream) {
  const float* src  = (const float*)d_in[0];
  const float* srcd = (const float*)d_in[1];
  const float* pos  = (const float*)d_in[2];
  const float* wA_i = (const float*)d_in[3];
  const float* bA_i = (const float*)d_in[4];
  const float* wA_d = (const float*)d_in[5];
  const float* bA_d = (const float*)d_in[6];
  const float* w1_i = (const float*)d_in[7];
  const float* b1_i = (const float*)d_in[8];
  const float* w2_i = (const float*)d_in[9];
  const float* b2_i = (const float*)d_in[10];
  const float* w1_d = (const float*)d_in[11];
  const float* b1_d = (const float*)d_in[12];
  const float* w2_d = (const float*)d_in[13];
  const float* b2_d = (const float*)d_in[14];
  const float* ln_i = (const float*)d_in[15];
  const float* ln_d = (const float*)d_in[16];

  float* out = (float*)d_out;
  float* ws  = (float*)d_ws;
  const size_t T4 = (size_t)M_ * D_;      // 4,194,304

  // ---- workspace layout (113 MB total) ----
  float* t_buf = ws;                       // [M,512] fp32
  float* xbuf  = ws + T4;                  // [M,512] fp32 (post-LN1, shared img/dpt)
  unsigned short* u = (unsigned short*)(ws + 2 * T4);
  unsigned short* src16  = u;              // T4
  unsigned short* srcd16 = u + T4;         // T4
  unsigned short* qkimg  = u + 2 * T4;     // [M,1024] (q,k img)
  unsigned short* vimg   = u + 4 * T4;     // [M,512]
  unsigned short* dptqkv = u + 5 * T4;     // [M,1536] (q,k,v dpt)
  unsigned short* w_i16  = u + 8 * T4;     // 4*DD
  unsigned short* w_d16  = w_i16 + 4 * DD_;
  unsigned short* w1i16  = w_d16 + 4 * DD_;
  unsigned short* w2i16  = w1i16 + FF_ * D_;
  unsigned short* w1d16  = w2i16 + D_ * FF_;
  unsigned short* w2d16  = w1d16 + FF_ * D_;
  // reuse (post-QKV): vt buffers in src16/srcd16 slots
  unsigned short* vt_i = src16;
  unsigned short* vt_d = srcd16;
  // reuse (post-attention): FFN hidden + LN bf16
  unsigned short* h16 = u + 2 * T4;        // 4*T4
  unsigned short* x16 = u + 6 * T4;        // T4
  // d_out overlays: qkin16 consumed before attention writes oi16 (same region)
  unsigned short* qkin16 = (unsigned short*)out;           // [0, T4)
  unsigned short* oi16   = (unsigned short*)out;           // [0, T4)
  unsigned short* od16   = (unsigned short*)out + 2 * T4;  // [2T4, 3T4)

  dim3 blk(256);

  // bf16 conversions
  cvt_kernel<<<4096, blk, 0, stream>>>(src,  src16,  (int)T4);
  cvt_kernel<<<4096, blk, 0, stream>>>(srcd, srcd16, (int)T4);
  cvt_kernel<<<1024, blk, 0, stream>>>(wA_i, w_i16, 4 * DD_);
  cvt_kernel<<<1024, blk, 0, stream>>>(wA_d, w_d16, 4 * DD_);
  cvt_kernel<<<1024, blk, 0, stream>>>(w1_i, w1i16, FF_ * D_);
  cvt_kernel<<<1024, blk, 0, stream>>>(w2_i, w2i16, D_ * FF_);
  cvt_kernel<<<1024, blk, 0, stream>>>(w1_d, w1d16, FF_ * D_);
  cvt_kernel<<<1024, blk, 0, stream>>>(w2_d, w2d16, D_ * FF_);
  addcvt_kernel<<<4096, blk, 0, stream>>>(src, pos, qkin16, (int)T4);

  // QKV projections (merged): img q+k (N=1024), img v, dpt q+k+v (N=1536)
  mgemm_kernel<<<dim3(8, 64),  blk, 0, stream>>>(qkin16, w_i16,           bA_i,        nullptr, nullptr, qkimg,  M_, 1024, 512, 0);
  mgemm_kernel<<<dim3(4, 64),  blk, 0, stream>>>(src16,  w_i16 + 2 * DD_, bA_i + 1024, nullptr, nullptr, vimg,   M_, 512,  512, 0);
  mgemm_kernel<<<dim3(12, 64), blk, 0, stream>>>(srcd16, w_d16,           bA_d,        nullptr, nullptr, dptqkv, M_, 1536, 512, 0);

  vtrans_kernel<<<dim3(16, 64), blk, 0, stream>>>(vimg, 512, vt_i);
  vtrans_kernel<<<dim3(16, 64), blk, 0, stream>>>(dptqkv + 1024, 1536, vt_d);

  attn_kernel<<<dim3(S_ / 64, B_ * H_), blk, 0, stream>>>(
      qkimg, qkimg + 512, 1024, vt_i, dptqkv, dptqkv + 512, 1536, vt_d, oi16, od16);

  // ---- img stream ----
  mgemm_kernel<<<dim3(4, 64), blk, 0, stream>>>(oi16, w_i16 + 3 * DD_, bA_i + 1536, src, t_buf, nullptr, M_, 512, 512, 0);
  ln_kernel<<<M_, blk, 0, stream>>>(t_buf, xbuf, x16, ln_i, ln_i + D_);
  mgemm_kernel<<<dim3(16, 64), blk, 0, stream>>>(x16, w1i16, b1_i, nullptr, nullptr, h16, M_, 2048, 512, 1);
  mgemm_kernel<<<dim3(4, 64), blk, 0, stream>>>(h16, w2i16, b2_i, xbuf, t_buf, nullptr, M_, 512, 2048, 0);
  ln_kernel<<<M_, blk, 0, stream>>>(t_buf, out, nullptr, ln_i + 2 * D_, ln_i + 3 * D_);

  // ---- depth stream ----
  mgemm_kernel<<<dim3(4, 64), blk, 0, stream>>>(od16, w_d16 + 3 * DD_, bA_d + 1536, srcd, t_buf, nullptr, M_, 512, 512, 0);
  ln_kernel<<<M_, blk, 0, stream>>>(t_buf, xbuf, x16, ln_d, ln_d + D_);
  mgemm_kernel<<<dim3(16, 64), blk, 0, stream>>>(x16, w1d16, b1_d, nullptr, nullptr, h16, M_, 2048, 512, 1);
  mgemm_kernel<<<dim3(4, 64), blk, 0, stream>>>(h16, w2d16, b2_d, xbuf, t_buf, nullptr, M_, 512, 2048, 0);
  ln_kernel<<<M_, blk, 0, stream>>>(t_buf, out + T4, nullptr, ln_d + 2 * D_, ln_d + 3 * D_);
}

// Round 4
// 468.134 us; speedup vs baseline: 7.5495x; 1.4546x over previous
//
#include <hip/hip_runtime.h>
#include <math.h>

// Problem constants
#define S_  1024
#define B_  8
#define D_  512
#define H_  8
#define HD_ 64
#define FF_ 2048
#define M_  8192   // S*B tokens; token r = s*B_ + b
#define DD_ (D_ * D_)

typedef __attribute__((ext_vector_type(8))) short short8;   // 8 x bf16
typedef __attribute__((ext_vector_type(4))) float f32x4;

static __device__ __forceinline__ unsigned short f2bf(float x) {
  union { float f; unsigned int u; } v; v.f = x;
  unsigned int r = v.u + 0x7fff + ((v.u >> 16) & 1);        // RNE
  return (unsigned short)(r >> 16);
}
static __device__ __forceinline__ float bf2f(unsigned short x) {
  union { unsigned int u; float f; } v; v.u = ((unsigned int)x) << 16;
  return v.f;
}
// pack two floats to 2 bf16 in one u32 (round-to-nearest-away; bias-free enough)
static __device__ __forceinline__ unsigned int pack_bf2(float a, float b) {
  union { float f; unsigned int u; } x, y; x.f = a; y.f = b;
  return ((x.u + 0x8000u) >> 16) | ((y.u + 0x8000u) & 0xffff0000u);
}
// async global->LDS, 16B/lane; LDS dest = wave-uniform base + lane*16
static __device__ __forceinline__ void gl_lds16(const unsigned short* g, unsigned short* l) {
  __builtin_amdgcn_global_load_lds((__attribute__((address_space(1))) void*)(g),
                                   (__attribute__((address_space(3))) void*)(l), 16, 0, 0);
}

// ---------------------------------------------------------------------------
// batched weight fp32->bf16 (6 jobs of exactly 1,048,576 elems)
// ---------------------------------------------------------------------------
struct CvtJobs { const float* in[6]; unsigned short* out[6]; };
__global__ __launch_bounds__(256) void wcvt_kernel(CvtJobs j) {
  int job = blockIdx.y;
  int i = (blockIdx.x * 256 + threadIdx.x) * 4;
  float4 v = *(const float4*)(j.in[job] + i);
  unsigned short u[4] = {f2bf(v.x), f2bf(v.y), f2bf(v.z), f2bf(v.w)};
  *(uint2*)(j.out[job] + i) = *(const uint2*)u;
}

// activations: job0 src->src16, job1 srcd->srcd16, job2 (src+pos)->qkin16
__global__ __launch_bounds__(256) void acvt_kernel(const float* __restrict__ src,
    const float* __restrict__ srcd, const float* __restrict__ pos,
    unsigned short* __restrict__ src16, unsigned short* __restrict__ srcd16,
    unsigned short* __restrict__ qkin16) {
  int job = blockIdx.y;
  int i = (blockIdx.x * 256 + threadIdx.x) * 4;
  const float* a = (job == 0) ? src : (job == 1) ? srcd : src;
  float4 v = *(const float4*)(a + i);
  if (job == 2) {
    float4 p = *(const float4*)(pos + i);
    v.x += p.x; v.y += p.y; v.z += p.z; v.w += p.w;
  }
  unsigned short* o = (job == 0) ? src16 : (job == 1) ? srcd16 : qkin16;
  unsigned short u[4] = {f2bf(v.x), f2bf(v.y), f2bf(v.z), f2bf(v.w)};
  *(uint2*)(o + i) = *(const uint2*)u;
}

// ---------------------------------------------------------------------------
// bf16 MFMA GEMM body (m97 structure): Y = X @ W^T + bias (+res) (+relu)
// 128x128 tile, BK=32, 256 thr = 4 waves (2x2 of 64x64), 16x16x32 MFMA.
// ---------------------------------------------------------------------------
static __device__ __forceinline__ void mgemm_body(
    const unsigned short* __restrict__ X, const unsigned short* __restrict__ W,
    const float* __restrict__ bias, const float* __restrict__ resf,
    const unsigned short* __restrict__ resb, unsigned short* __restrict__ Yb,
    float* __restrict__ Yf, int N, int K, int relu, int bx, int by,
    unsigned short* As, unsigned short* Bs)
{
  int tid = threadIdx.x;
  int lane = tid & 63, w = tid >> 6;
  int ml = lane & 15, g = lane >> 4;
  int wm = w >> 1, wn = w & 1;
  int m0 = by * 128, n0 = bx * 128;

  int lrow = w * 32 + (lane >> 2);
  int lcol = (lane & 3) * 8;
  const unsigned short* gA = X + (size_t)(m0 + lrow) * K + lcol;
  const unsigned short* gB = W + (size_t)(n0 + lrow) * K + lcol;
  unsigned short* lA = As + w * 1024;
  unsigned short* lB = Bs + w * 1024;

  f32x4 acc[4][4];
  #pragma unroll
  for (int i = 0; i < 4; i++)
    #pragma unroll
    for (int j = 0; j < 4; j++) acc[i][j] = (f32x4){0.f, 0.f, 0.f, 0.f};

  for (int k0 = 0; k0 < K; k0 += 32) {
    __syncthreads();
    gl_lds16(gA + k0, lA);
    gl_lds16(gA + k0 + (size_t)16 * K, lA + 512);
    gl_lds16(gB + k0, lB);
    gl_lds16(gB + k0 + (size_t)16 * K, lB + 512);
    __syncthreads();

    short8 af[4], bfr[4];
    #pragma unroll
    for (int i = 0; i < 4; i++)
      af[i] = *(const short8*)&As[(wm * 64 + i * 16 + ml) * 32 + g * 8];
    #pragma unroll
    for (int j = 0; j < 4; j++)
      bfr[j] = *(const short8*)&Bs[(wn * 64 + j * 16 + ml) * 32 + g * 8];
    #pragma unroll
    for (int i = 0; i < 4; i++)
      #pragma unroll
      for (int j = 0; j < 4; j++)
        acc[i][j] = __builtin_amdgcn_mfma_f32_16x16x32_bf16(af[i], bfr[j], acc[i][j], 0, 0, 0);
  }

  #pragma unroll
  for (int i = 0; i < 4; i++) {
    int grow = m0 + wm * 64 + i * 16 + g * 4;
    #pragma unroll
    for (int j = 0; j < 4; j++) {
      int gcol = n0 + wn * 64 + j * 16 + ml;
      float bv = bias[gcol];
      #pragma unroll
      for (int r = 0; r < 4; r++) {
        size_t idx = (size_t)(grow + r) * N + gcol;
        float v = acc[i][j][r] + bv;
        if (resf) v += resf[idx];
        if (resb) v += bf2f(resb[idx]);
        if (relu) v = fmaxf(v, 0.0f);
        if (Yb) Yb[idx] = f2bf(v);
        if (Yf) Yf[idx] = v;
      }
    }
  }
}

// QKV mega-launch: bx<8 img q,k (N=1024) | bx<12 img v (N=512) | else dpt qkv (N=1536)
__global__ __launch_bounds__(256) void qkv_kernel(
    const unsigned short* __restrict__ qkin, const unsigned short* __restrict__ src16,
    const unsigned short* __restrict__ srcd16,
    const unsigned short* __restrict__ w_i, const unsigned short* __restrict__ w_d,
    const float* __restrict__ bA_i, const float* __restrict__ bA_d,
    unsigned short* __restrict__ qkimg, unsigned short* __restrict__ vimg,
    unsigned short* __restrict__ dptqkv)
{
  __shared__ unsigned short As[128 * 32];
  __shared__ unsigned short Bs[128 * 32];
  int bx = blockIdx.x, by = blockIdx.y;
  if (bx < 8)
    mgemm_body(qkin, w_i, bA_i, nullptr, nullptr, qkimg, nullptr, 1024, 512, 0, bx, by, As, Bs);
  else if (bx < 12)
    mgemm_body(src16, w_i + 2 * DD_, bA_i + 1024, nullptr, nullptr, vimg, nullptr, 512, 512, 0, bx - 8, by, As, Bs);
  else
    mgemm_body(srcd16, w_d, bA_d, nullptr, nullptr, dptqkv, nullptr, 1536, 512, 0, bx - 12, by, As, Bs);
}

// img/dpt pair GEMM: blockIdx.z selects stream
__global__ __launch_bounds__(256) void pgemm_kernel(
    const unsigned short* __restrict__ X0, const unsigned short* __restrict__ X1,
    const unsigned short* __restrict__ W0, const unsigned short* __restrict__ W1,
    const float* __restrict__ b0, const float* __restrict__ b1,
    const float* __restrict__ rf0, const float* __restrict__ rf1,
    const unsigned short* __restrict__ rb0, const unsigned short* __restrict__ rb1,
    unsigned short* __restrict__ Y0, unsigned short* __restrict__ Y1,
    int N, int K, int relu)
{
  __shared__ unsigned short As[128 * 32];
  __shared__ unsigned short Bs[128 * 32];
  int z = blockIdx.z;
  mgemm_body(z ? X1 : X0, z ? W1 : W0, z ? b1 : b0, z ? rf1 : rf0,
             z ? rb1 : rb0, z ? Y1 : Y0, nullptr, N, K, relu,
             blockIdx.x, blockIdx.y, As, Bs);
}

// ---------------------------------------------------------------------------
// V transpose pair: v [M, ld] token-major head slice -> vt [B*H][64][1024]
// ---------------------------------------------------------------------------
__global__ __launch_bounds__(256) void vtrans_kernel(
    const unsigned short* __restrict__ v0, int ld0, unsigned short* __restrict__ vt0,
    const unsigned short* __restrict__ v1, int ld1, unsigned short* __restrict__ vt1)
{
  __shared__ unsigned short tile[64][72];
  const unsigned short* v = blockIdx.z ? v1 : v0;
  unsigned short* vt = blockIdx.z ? vt1 : vt0;
  int ld = blockIdx.z ? ld1 : ld0;
  int bh = blockIdx.y, b = bh >> 3, h = bh & 7;
  int s0 = blockIdx.x * 64;
  int tid = threadIdx.x;
  #pragma unroll
  for (int t = 0; t < 2; t++) {
    int idx = t * 256 + tid;
    int i = idx >> 3, c8 = (idx & 7) * 8;
    *(uint4*)&tile[i][c8] =
        *(const uint4*)(v + ((size_t)(s0 + i) * B_ + b) * ld + h * HD_ + c8);
  }
  __syncthreads();
  int hd = tid >> 2, j0 = (tid & 3) * 16;
  unsigned short tmp[16];
  #pragma unroll
  for (int j = 0; j < 16; j++) tmp[j] = tile[j0 + j][hd];
  unsigned short* dst = vt + ((size_t)bh * HD_ + hd) * S_ + s0 + j0;
  *(uint4*)(dst) = *(const uint4*)&tmp[0];
  *(uint4*)(dst + 8) = *(const uint4*)&tmp[8];
}

// ---------------------------------------------------------------------------
// LayerNorm pair, bf16 in: rows 0..8191 stream0, 8192..16383 stream1
// ---------------------------------------------------------------------------
__global__ __launch_bounds__(256) void ln16_kernel(
    const unsigned short* __restrict__ X0, const unsigned short* __restrict__ X1,
    unsigned short* __restrict__ Yb0, unsigned short* __restrict__ Yb1,
    float* __restrict__ Yf0, float* __restrict__ Yf1,
    const float* __restrict__ gb0, const float* __restrict__ gb1)
{
  int row = blockIdx.x, tid = threadIdx.x;
  int strm = row >> 13, r = row & 8191;
  const unsigned short* X = strm ? X1 : X0;
  unsigned short* Yb = strm ? Yb1 : Yb0;
  float* Yf = strm ? Yf1 : Yf0;
  const float* gb = strm ? gb1 : gb0;       // gamma at [0,512), beta at [512,1024)

  ushort2 xv = *(const ushort2*)(X + (size_t)r * D_ + 2 * tid);
  float v0 = bf2f(xv.x), v1 = bf2f(xv.y);
  float s = v0 + v1, q = v0 * v0 + v1 * v1;
  #pragma unroll
  for (int msk = 1; msk < 64; msk <<= 1) {
    s += __shfl_xor(s, msk);
    q += __shfl_xor(q, msk);
  }
  __shared__ float ss[4], qs[4];
  int wid = tid >> 6;
  if ((tid & 63) == 0) { ss[wid] = s; qs[wid] = q; }
  __syncthreads();
  s = ss[0] + ss[1] + ss[2] + ss[3];
  q = qs[0] + qs[1] + qs[2] + qs[3];
  float mean = s * (1.0f / D_);
  float var  = q * (1.0f / D_) - mean * mean;
  float inv  = rsqrtf(var + 1e-5f);
  float2 gg = *(const float2*)(gb + 2 * tid);
  float2 bb = *(const float2*)(gb + 512 + 2 * tid);
  float o0 = (v0 - mean) * inv * gg.x + bb.x;
  float o1 = (v1 - mean) * inv * gg.y + bb.y;
  if (Yb) {
    unsigned int pk = pack_bf2(o0, o1);
    // RNE for output accuracy:
    unsigned short u[2] = {f2bf(o0), f2bf(o1)};
    *(unsigned int*)(Yb + (size_t)r * D_ + 2 * tid) = *(const unsigned int*)u;
    (void)pk;
  }
  if (Yf) {
    float2 o; o.x = o0; o.y = o1;
    *(float2*)(Yf + (size_t)r * D_ + 2 * tid) = o;
  }
}

// ---------------------------------------------------------------------------
// MFMA dual-stream cross-blended flash attention v2.
// Q-tile 128/block (4 waves x 32 q, 2 msets of 16). K-tiles of 64.
// QK computed TRANSPOSED (A=K,B=Q -> C'[key][q]) so P packs along regs ->
// Pl written as b64; K/V staged via global_load_lds into unpadded [64][64]
// tiles with XOR-chunk swizzle (conflict-free frag reads).
// Plain exp (logits tiny) == exact softmax. 4 accumulators, blend at end.
// ---------------------------------------------------------------------------
__global__ __launch_bounds__(256, 2) void attn_kernel(
    const unsigned short* __restrict__ Qi, const unsigned short* __restrict__ Ki, int ldi,
    const unsigned short* __restrict__ Vti,
    const unsigned short* __restrict__ Qd, const unsigned short* __restrict__ Kd, int ldd,
    const unsigned short* __restrict__ Vtd,
    unsigned short* __restrict__ oi, unsigned short* __restrict__ od)
{
  __shared__ __align__(16) unsigned short Kls[2][64 * 64];   // [stream][key][dim] swizzled
  __shared__ __align__(16) unsigned short Vls[2][64 * 64];   // [stream][dim][key] swizzled
  __shared__ __align__(16) unsigned short Pl[4][2][16 * 80]; // [wave][stream][q][key] pad 80

  int tid = threadIdx.x;
  int bh = blockIdx.y, b = bh >> 3, h = bh & 7;
  int q0 = blockIdx.x * 128;
  int lane = tid & 63, w = tid >> 6;
  int ml = lane & 15, g = lane >> 4;
  int mx = ml & 7;                       // row-swizzle term for frag reads

  // Q fragments: [mset][stream][khalf]; lane holds Q[q=ml of mset][dims g*8(+32)]
  short8 qf[2][2][2];
  #pragma unroll
  for (int t = 0; t < 2; t++) {
    size_t tok = (size_t)(q0 + w * 32 + t * 16 + ml) * B_ + b;
    const unsigned short* qa_i = Qi + tok * ldi + h * HD_ + g * 8;
    const unsigned short* qa_d = Qd + tok * ldd + h * HD_ + g * 8;
    qf[t][0][0] = *(const short8*)(qa_i);  qf[t][0][1] = *(const short8*)(qa_i + 32);
    qf[t][1][0] = *(const short8*)(qa_d);  qf[t][1][1] = *(const short8*)(qa_d + 32);
  }

  // staging role per wave: w0->K img, w1->K dpt, w2->V img, w3->V dpt
  int srow = lane >> 3;                  // 0..7
  int chg = (lane & 7) ^ srow;           // global chunk for this lane's LDS slot
  const unsigned short* gbase; size_t s1, s2; unsigned short* lbase;
  if (w == 0)      { gbase = Ki  + ((size_t)srow * B_ + b) * ldi + h * HD_ + chg * 8; s1 = (size_t)B_ * ldi; s2 = s1; lbase = &Kls[0][0]; }
  else if (w == 1) { gbase = Kd  + ((size_t)srow * B_ + b) * ldd + h * HD_ + chg * 8; s1 = (size_t)B_ * ldd; s2 = s1; lbase = &Kls[1][0]; }
  else if (w == 2) { gbase = Vti + (size_t)bh * HD_ * S_ + (size_t)srow * S_ + chg * 8; s1 = S_; s2 = 1; lbase = &Vls[0][0]; }
  else             { gbase = Vtd + (size_t)bh * HD_ * S_ + (size_t)srow * S_ + chg * 8; s1 = S_; s2 = 1; lbase = &Vls[1][0]; }

  f32x4 acc4[2][4][4];                   // [mset][combo: ii,di,id,dd][hd-tile]
  #pragma unroll
  for (int t = 0; t < 2; t++)
    #pragma unroll
    for (int cb = 0; cb < 4; cb++)
      #pragma unroll
      for (int n = 0; n < 4; n++) acc4[t][cb][n] = (f32x4){0.f, 0.f, 0.f, 0.f};
  float lI[2] = {0.f, 0.f}, lD[2] = {0.f, 0.f};
  const float scale = 0.125f;

  for (int kt = 0; kt < S_ / 64; kt++) {
    int k0 = kt * 64;
    __syncthreads();
    {
      const unsigned short* gp = gbase + (size_t)k0 * s2;
      #pragma unroll
      for (int rr = 0; rr < 8; rr++)
        gl_lds16(gp + (size_t)rr * 8 * s1, lbase + rr * 512);
    }
    __syncthreads();

    #pragma unroll
    for (int t = 0; t < 2; t++) {
      // ---- QK^T transposed: C'[key][q], key tiles n of 16 ----
      #pragma unroll
      for (int st = 0; st < 2; st++) {
        float* ls = st ? &lD[t] : &lI[t];
        const unsigned short* Kt = &Kls[st][0];
        #pragma unroll
        for (int n = 0; n < 4; n++) {
          int rbase = (n * 16 + ml) * 64;
          short8 kf0 = *(const short8*)&Kt[rbase + ((g ^ mx) * 8)];
          short8 kf1 = *(const short8*)&Kt[rbase + (((g + 4) ^ mx) * 8)];
          f32x4 a = (f32x4){0.f, 0.f, 0.f, 0.f};
          a = __builtin_amdgcn_mfma_f32_16x16x32_bf16(kf0, qf[t][st][0], a, 0, 0, 0);
          a = __builtin_amdgcn_mfma_f32_16x16x32_bf16(kf1, qf[t][st][1], a, 0, 0, 0);
          float p0 = __expf(a[0] * scale), p1 = __expf(a[1] * scale);
          float p2 = __expf(a[2] * scale), p3 = __expf(a[3] * scale);
          *ls += (p0 + p1) + (p2 + p3);
          uint2 pk; pk.x = pack_bf2(p0, p1); pk.y = pack_bf2(p2, p3);
          *(uint2*)&Pl[w][st][ml * 80 + n * 16 + g * 4] = pk;   // P[q=ml][key n*16+g*4..+3]
        }
      }
      // ---- PV: 4 combos, key-dim 64 in 2 chunks of 32 ----
      #pragma unroll
      for (int c = 0; c < 2; c++) {
        short8 pI = *(const short8*)&Pl[w][0][ml * 80 + g * 8 + c * 32];
        short8 pD = *(const short8*)&Pl[w][1][ml * 80 + g * 8 + c * 32];
        #pragma unroll
        for (int n = 0; n < 4; n++) {
          int rbase = (n * 16 + ml) * 64;
          int sc = (((g + 4 * c) ^ mx)) * 8;
          short8 vI = *(const short8*)&Vls[0][rbase + sc];
          short8 vD = *(const short8*)&Vls[1][rbase + sc];
          acc4[t][0][n] = __builtin_amdgcn_mfma_f32_16x16x32_bf16(pI, vI, acc4[t][0][n], 0, 0, 0);
          acc4[t][1][n] = __builtin_amdgcn_mfma_f32_16x16x32_bf16(pD, vI, acc4[t][1][n], 0, 0, 0);
          acc4[t][2][n] = __builtin_amdgcn_mfma_f32_16x16x32_bf16(pI, vD, acc4[t][2][n], 0, 0, 0);
          acc4[t][3][n] = __builtin_amdgcn_mfma_f32_16x16x32_bf16(pD, vD, acc4[t][3][n], 0, 0, 0);
        }
      }
    }
  }

  // denominators: lane holds partial (its 16 keys/ktile) for q=ml; reduce over g
  #pragma unroll
  for (int t = 0; t < 2; t++) {
    lI[t] += __shfl_xor(lI[t], 16);  lI[t] += __shfl_xor(lI[t], 32);
    lD[t] += __shfl_xor(lD[t], 16);  lD[t] += __shfl_xor(lD[t], 32);
  }
  #pragma unroll
  for (int t = 0; t < 2; t++) {
    float invI = 1.0f / lI[t], invD = 1.0f / lD[t];
    #pragma unroll
    for (int r = 0; r < 4; r++) {
      float iI = __shfl(invI, g * 4 + r, 16);     // denom lives at lane ml == q row
      float iD = __shfl(invD, g * 4 + r, 16);
      int qrow = q0 + w * 32 + t * 16 + g * 4 + r;
      size_t ob = ((size_t)qrow * B_ + b) * D_ + h * HD_;
      #pragma unroll
      for (int n = 0; n < 4; n++) {
        oi[ob + n * 16 + ml] = f2bf(0.5f * (acc4[t][0][n][r] * iI + acc4[t][1][n][r] * iD));
        od[ob + n * 16 + ml] = f2bf(0.5f * (acc4[t][3][n][r] * iD + acc4[t][2][n][r] * iI));
      }
    }
  }
}

// ---------------------------------------------------------------------------
extern "C" void kernel_launch(void* const* d_in, const int* in_sizes, int n_in,
                              void* d_out, int out_size, void* d_ws, size_t ws_size,
                              hipStream_t stream) {
  const float* src  = (const float*)d_in[0];
  const float* srcd = (const float*)d_in[1];
  const float* pos  = (const float*)d_in[2];
  const float* wA_i = (const float*)d_in[3];
  const float* bA_i = (const float*)d_in[4];
  const float* wA_d = (const float*)d_in[5];
  const float* bA_d = (const float*)d_in[6];
  const float* w1_i = (const float*)d_in[7];
  const float* b1_i = (const float*)d_in[8];
  const float* w2_i = (const float*)d_in[9];
  const float* b2_i = (const float*)d_in[10];
  const float* w1_d = (const float*)d_in[11];
  const float* b1_d = (const float*)d_in[12];
  const float* w2_d = (const float*)d_in[13];
  const float* b2_d = (const float*)d_in[14];
  const float* ln_i = (const float*)d_in[15];
  const float* ln_d = (const float*)d_in[16];

  float* out = (float*)d_out;
  unsigned short* u = (unsigned short*)d_ws;
  const size_t T4 = (size_t)M_ * D_;          // 4,194,304
  const size_t WSZ = (size_t)FF_ * D_;        // 1,048,576 (== 4*DD_)

  // ---- workspace layout (units of T4 ushorts = 8.39 MB; total 113.2 MB) ----
  unsigned short* src16  = u;                 // [0,1) -> vt_i after QKV
  unsigned short* srcd16 = u + T4;            // [1,2) -> vt_d after QKV
  unsigned short* qkimg  = u + 2 * T4;        // [2,4)  [M,1024]
  unsigned short* vimg   = u + 4 * T4;        // [4,5)  [M,512]
  unsigned short* dptqkv = u + 5 * T4;        // [5,8)  [M,1536]
  unsigned short* w_i16  = u + 8 * T4;        // weights: 6 x 1,048,576
  unsigned short* w_d16  = w_i16 + WSZ;
  unsigned short* w1i16  = w_d16 + WSZ;
  unsigned short* w2i16  = w1i16 + WSZ;
  unsigned short* w1d16  = w2i16 + WSZ;
  unsigned short* w2d16  = w1d16 + WSZ;
  unsigned short* t16_i  = w2d16 + WSZ;       // [9.5,10.5) pre-LN bf16
  unsigned short* t16_d  = t16_i + T4;        // [10.5,11.5)
  unsigned short* x16_i  = t16_d + T4;        // [11.5,12.5) post-LN1
  unsigned short* x16_d  = x16_i + T4;        // [12.5,13.5)
  unsigned short* vt_i   = src16;             // reuse after QKV
  unsigned short* vt_d   = srcd16;
  unsigned short* h16_i  = u;                 // [0,4) FFN hidden (post-attn reuse)
  unsigned short* h16_d  = u + 4 * T4;        // [4,8)
  // d_out overlays (consumed before final LN writes)
  unsigned short* qkin16 = (unsigned short*)out;          // bytes [0, 2T4)
  unsigned short* oi16   = (unsigned short*)out;          // bytes [0, 2T4)
  unsigned short* od16   = (unsigned short*)out + T4;     // bytes [2T4, 4T4)

  dim3 blk(256);

  CvtJobs cj;
  cj.in[0] = wA_i; cj.out[0] = w_i16;
  cj.in[1] = wA_d; cj.out[1] = w_d16;
  cj.in[2] = w1_i; cj.out[2] = w1i16;
  cj.in[3] = w2_i; cj.out[3] = w2i16;
  cj.in[4] = w1_d; cj.out[4] = w1d16;
  cj.in[5] = w2_d; cj.out[5] = w2d16;
  wcvt_kernel<<<dim3(1024, 6), blk, 0, stream>>>(cj);
  acvt_kernel<<<dim3(4096, 3), blk, 0, stream>>>(src, srcd, pos, src16, srcd16, qkin16);

  qkv_kernel<<<dim3(24, 64), blk, 0, stream>>>(qkin16, src16, srcd16, w_i16, w_d16,
                                               bA_i, bA_d, qkimg, vimg, dptqkv);
  vtrans_kernel<<<dim3(16, 64, 2), blk, 0, stream>>>(vimg, 512, vt_i, dptqkv + 1024, 1536, vt_d);

  attn_kernel<<<dim3(S_ / 128, B_ * H_), blk, 0, stream>>>(
      qkimg, qkimg + 512, 1024, vt_i, dptqkv, dptqkv + 512, 1536, vt_d, oi16, od16);

  // out-proj + residual(src fp32) -> pre-LN bf16
  pgemm_kernel<<<dim3(4, 64, 2), blk, 0, stream>>>(
      oi16, od16, w_i16 + 3 * DD_, w_d16 + 3 * DD_, bA_i + 1536, bA_d + 1536,
      src, srcd, nullptr, nullptr, t16_i, t16_d, 512, 512, 0);
  ln16_kernel<<<2 * M_, blk, 0, stream>>>(t16_i, t16_d, x16_i, x16_d,
                                          nullptr, nullptr, ln_i, ln_d);
  pgemm_kernel<<<dim3(16, 64, 2), blk, 0, stream>>>(
      x16_i, x16_d, w1i16, w1d16, b1_i, b1_d,
      nullptr, nullptr, nullptr, nullptr, h16_i, h16_d, 2048, 512, 1);
  pgemm_kernel<<<dim3(4, 64, 2), blk, 0, stream>>>(
      h16_i, h16_d, w2i16, w2d16, b2_i, b2_d,
      nullptr, nullptr, x16_i, x16_d, t16_i, t16_d, 512, 2048, 0);
  ln16_kernel<<<2 * M_, blk, 0, stream>>>(t16_i, t16_d, nullptr, nullptr,
                                          out, out + T4, ln_i + 2 * D_, ln_d + 2 * D_);
}